// Round 2
// baseline (16421.288 us; speedup 1.0000x reference)
//
#include <hip/hip_runtime.h>
#include <hip/hip_bf16.h>
#include <type_traits>

#define LAYERS 4
#define D      768
#define FF     3072
#define NH     12
#define HD     64
#define SEQ    4096
#define BATCH  4
#define WIN    128
#define NC     (SEQ / WIN)        // 32
#define NTOK   (BATCH * SEQ)      // 16384

using bf16 = __hip_bfloat16;

__device__ __forceinline__ float b2f(unsigned short u) {
    return __uint_as_float(((unsigned)u) << 16);
}

// ---------- load converters ----------
__device__ __forceinline__ float ld_cvt(const float* p) { return *p; }
__device__ __forceinline__ float ld_cvt(const bf16* p) { return __bfloat162float(*p); }
__device__ __forceinline__ void st_cvt(float* p, float v) { *p = v; }
__device__ __forceinline__ void st_cvt(bf16* p, float v) { *p = __float2bfloat16(v); }

// ---------- GEMM: C = epilogue(A @ W + bias) ----------
// A: [rows, K] (TA), W: [K, Ncols] f32 row-major, bias: [Ncols].
// 64x64 tile, 256 threads, 4x4 micro-tile per thread.
// QKV=1: scatter to per-batch [NH, SEQ, HD] bf16 layout (col = h*64+hd), with scale.
template<int RELU, int QKV, typename TA, typename TC>
__global__ __launch_bounds__(256)
void gemm_kernel(const TA* __restrict__ A, const float* __restrict__ Wt,
                 const float* __restrict__ bias, TC* __restrict__ C,
                 int K, int Ncols, float scale)
{
    __shared__ float As[64][20];   // row stride 80B (16B-aligned), 2-way max (free)
    __shared__ float Bs[16][68];   // row stride 272B (16B-aligned)
    const int row0 = blockIdx.x * 64;
    const int col0 = blockIdx.y * 64;
    const int tid  = threadIdx.x;
    const int tx = tid & 15, ty = tid >> 4;
    const int ar = tid >> 2, ak = (tid & 3) * 4;   // A-tile load coords (64x16)
    const int br = tid >> 4, bc = (tid & 15) * 4;  // B-tile load coords (16x64)

    float acc[4][4] = {};
    for (int k0 = 0; k0 < K; k0 += 16) {
        if constexpr (std::is_same<TA, float>::value) {
            float4 a4 = *(const float4*)(A + (size_t)(row0 + ar) * K + k0 + ak);
            *(float4*)&As[ar][ak] = a4;
        } else {
            // 4 bf16 = 8 bytes, aligned (ak multiple of 4, K multiple of 4)
            const ushort4 a4 = *(const ushort4*)((const unsigned short*)A +
                                                 (size_t)(row0 + ar) * K + k0 + ak);
            As[ar][ak + 0] = b2f(a4.x);
            As[ar][ak + 1] = b2f(a4.y);
            As[ar][ak + 2] = b2f(a4.z);
            As[ar][ak + 3] = b2f(a4.w);
        }
        float4 b4 = *(const float4*)(Wt + (size_t)(k0 + br) * Ncols + col0 + bc);
        *(float4*)&Bs[br][bc] = b4;
        __syncthreads();
        #pragma unroll
        for (int kk = 0; kk < 16; ++kk) {
            float a[4], b[4];
            #pragma unroll
            for (int i = 0; i < 4; ++i) a[i] = As[ty * 4 + i][kk];
            #pragma unroll
            for (int j = 0; j < 4; ++j) b[j] = Bs[kk][tx * 4 + j];
            #pragma unroll
            for (int i = 0; i < 4; ++i)
                #pragma unroll
                for (int j = 0; j < 4; ++j)
                    acc[i][j] += a[i] * b[j];
        }
        __syncthreads();
    }
    #pragma unroll
    for (int i = 0; i < 4; ++i) {
        const int r = row0 + ty * 4 + i;           // row within this batch slice
        #pragma unroll
        for (int j = 0; j < 4; ++j) {
            const int c = col0 + tx * 4 + j;
            float val = acc[i][j] + bias[c];
            if (RELU) val = fmaxf(val, 0.f);
            val *= scale;
            if (QKV) {
                const int h_ = c >> 6, d_ = c & (HD - 1);
                st_cvt(&C[((size_t)h_ * SEQ + r) * HD + d_], val);
            } else {
                st_cvt(&C[(size_t)r * Ncols + c], val);
            }
        }
    }
}

// ---------- sliding-window attention (flash-style, online softmax) ----------
// per-batch: grid (NC, NH), block 128 = one query row per thread.
// q,k,v: bf16 [NH, SEQ, HD]; out: bf16 [SEQ, D] (heads merged)
__global__ __launch_bounds__(128)
void attn_kernel(const bf16* __restrict__ q, const bf16* __restrict__ k,
                 const bf16* __restrict__ v, bf16* __restrict__ out)
{
    const int c = blockIdx.x, h = blockIdx.y;
    const int qi = threadIdx.x;                 // 0..127
    const int qpos = c * WIN + qi;
    const size_t headoff = (size_t)h * SEQ * HD;

    float qreg[HD];
    {
        const unsigned short* qrow = (const unsigned short*)q + headoff + (size_t)qpos * HD;
        #pragma unroll
        for (int e = 0; e < 8; ++e) {
            uint4 raw = *(const uint4*)(qrow + e * 8);
            const unsigned short* u = (const unsigned short*)&raw;
            #pragma unroll
            for (int t = 0; t < 8; ++t) qreg[e * 8 + t] = b2f(u[t]);
        }
    }

    float acc[HD] = {};
    float m = -1e30f, l = 0.f;

    __shared__ float Ks[32][HD];
    __shared__ float Vs[32][HD];
    const unsigned short* kb = (const unsigned short*)k + headoff;
    const unsigned short* vb = (const unsigned short*)v + headoff;

    for (int t0 = 0; t0 < 3 * WIN; t0 += 32) {
        __syncthreads();
        // stage 32 keys/values: 2048 bf16 each = 256 x 16B loads over 128 threads
        #pragma unroll
        for (int e = 0; e < 2; ++e) {
            const int idx = threadIdx.x + e * 128;       // 0..255
            const int j = idx >> 3;                      // key row 0..31
            const int dd = (idx & 7) * 8;                // elem offset 0..56
            const int kpos = c * WIN + t0 + j - WIN;
            float kf[8] = {}, vf[8] = {};
            if (kpos >= 0 && kpos < SEQ) {
                uint4 kr = *(const uint4*)(kb + (size_t)kpos * HD + dd);
                uint4 vr = *(const uint4*)(vb + (size_t)kpos * HD + dd);
                const unsigned short* ku = (const unsigned short*)&kr;
                const unsigned short* vu = (const unsigned short*)&vr;
                #pragma unroll
                for (int t = 0; t < 8; ++t) { kf[t] = b2f(ku[t]); vf[t] = b2f(vu[t]); }
            }
            #pragma unroll
            for (int t = 0; t < 8; ++t) { Ks[j][dd + t] = kf[t]; Vs[j][dd + t] = vf[t]; }
        }
        __syncthreads();
        // uniform j loop keeps lanes in lockstep -> LDS reads broadcast
        for (int j = 0; j < 32; ++j) {
            const int kj = t0 + j;
            const int kpos = c * WIN + kj - WIN;
            if (kj < qi || kj > qi + 2 * WIN || kpos < 0 || kpos >= SEQ) continue;
            float s = 0.f;
            #pragma unroll
            for (int d = 0; d < HD; ++d) s += qreg[d] * Ks[j][d];
            const float mn = fmaxf(m, s);
            const float corr = __expf(m - mn);
            const float p = __expf(s - mn);
            l = l * corr + p;
            #pragma unroll
            for (int d = 0; d < HD; ++d) acc[d] = acc[d] * corr + p * Vs[j][d];
            m = mn;
        }
    }
    const float inv = 1.f / l;
    bf16* orow = out + (size_t)qpos * D + h * HD;
    #pragma unroll
    for (int d = 0; d < HD; ++d) orow[d] = __float2bfloat16(acc[d] * inv);
}

// ---------- fused residual add + LayerNorm ----------
// per-batch: one block per row (768 elems), 256 threads. h is bf16.
__global__ __launch_bounds__(256)
void add_ln_kernel(const float* __restrict__ xin, const bf16* __restrict__ h,
                   float* __restrict__ xout,
                   const float* __restrict__ g, const float* __restrict__ beta)
{
    const int row = blockIdx.x;
    __shared__ float buf[D];
    __shared__ float wsum[4], wsum2[4];
    const float* xr = xin + (size_t)row * D;
    const bf16* hr = h + (size_t)row * D;
    float s = 0.f, s2 = 0.f;
    #pragma unroll
    for (int e = 0; e < 3; ++e) {
        const int i = threadIdx.x + e * 256;
        const float t = xr[i] + __bfloat162float(hr[i]);
        buf[i] = t;
        s += t; s2 += t * t;
    }
    #pragma unroll
    for (int off = 32; off > 0; off >>= 1) {
        s  += __shfl_down(s, off);
        s2 += __shfl_down(s2, off);
    }
    const int wid = threadIdx.x >> 6, lane = threadIdx.x & 63;
    if (lane == 0) { wsum[wid] = s; wsum2[wid] = s2; }
    __syncthreads();
    if (threadIdx.x == 0) {
        const float S  = wsum[0] + wsum[1] + wsum[2] + wsum[3];
        const float S2 = wsum2[0] + wsum2[1] + wsum2[2] + wsum2[3];
        const float mean = S * (1.f / D);
        const float var  = S2 * (1.f / D) - mean * mean;
        wsum[0]  = mean;
        wsum2[0] = rsqrtf(var + 1e-5f);
    }
    __syncthreads();
    const float mean = wsum[0], inv = wsum2[0];
    #pragma unroll
    for (int e = 0; e < 3; ++e) {
        const int i = threadIdx.x + e * 256;
        xout[(size_t)row * D + i] = (buf[i] - mean) * inv * g[i] + beta[i];
    }
}

extern "C" void kernel_launch(void* const* d_in, const int* in_sizes, int n_in,
                              void* d_out, int out_size, void* d_ws, size_t ws_size,
                              hipStream_t stream)
{
    const float* x0  = (const float*)d_in[0];
    const float* Wq  = (const float*)d_in[1];
    const float* bq  = (const float*)d_in[2];
    const float* Wk  = (const float*)d_in[3];
    const float* bk  = (const float*)d_in[4];
    const float* Wv  = (const float*)d_in[5];
    const float* bv  = (const float*)d_in[6];
    const float* W1  = (const float*)d_in[7];
    const float* b1  = (const float*)d_in[8];
    const float* W2  = (const float*)d_in[9];
    const float* b2  = (const float*)d_in[10];
    const float* g1  = (const float*)d_in[11];
    const float* be1 = (const float*)d_in[12];
    const float* g2  = (const float*)d_in[13];
    const float* be2 = (const float*)d_in[14];
    float* out = (float*)d_out;

    // Per-batch workspace: 48 MB total (bf16 intermediates).
    char* ws = (char*)d_ws;
    bf16* qb  = (bf16*)ws;  ws += (size_t)NH * SEQ * HD * sizeof(bf16);   // 6 MB
    bf16* kb  = (bf16*)ws;  ws += (size_t)NH * SEQ * HD * sizeof(bf16);   // 6 MB
    bf16* vb  = (bf16*)ws;  ws += (size_t)NH * SEQ * HD * sizeof(bf16);   // 6 MB
    bf16* hb  = (bf16*)ws;  ws += (size_t)SEQ * D * sizeof(bf16);         // 6 MB
    bf16* mid = (bf16*)ws;                                                 // 24 MB

    const dim3 gproj(SEQ / 64, D / 64);     // (64, 12)
    const dim3 gff1(SEQ / 64, FF / 64);     // (64, 48)
    const dim3 gattn(NC, NH);               // (32, 12)

    for (int l = 0; l < LAYERS; ++l) {
        const float* xsrc = (l == 0) ? x0 : out;
        for (int b = 0; b < BATCH; ++b) {
            const float* xin = xsrc + (size_t)b * SEQ * D;
            float* xo = out + (size_t)b * SEQ * D;
            gemm_kernel<0, 1, float, bf16><<<gproj, 256, 0, stream>>>(
                xin, Wq + (size_t)l * D * D, bq + (size_t)l * D, qb, D, D, 0.125f);
            gemm_kernel<0, 1, float, bf16><<<gproj, 256, 0, stream>>>(
                xin, Wk + (size_t)l * D * D, bk + (size_t)l * D, kb, D, D, 1.0f);
            gemm_kernel<0, 1, float, bf16><<<gproj, 256, 0, stream>>>(
                xin, Wv + (size_t)l * D * D, bv + (size_t)l * D, vb, D, D, 1.0f);
            attn_kernel<<<gattn, 128, 0, stream>>>(qb, kb, vb, hb);
            add_ln_kernel<<<SEQ, 256, 0, stream>>>(xin, hb, xo,
                g1 + (size_t)l * D, be1 + (size_t)l * D);
            gemm_kernel<1, 0, float, bf16><<<gff1, 256, 0, stream>>>(
                xo, W1 + (size_t)l * D * FF, b1 + (size_t)l * FF, mid, D, FF, 1.0f);
            gemm_kernel<0, 0, bf16, bf16><<<gproj, 256, 0, stream>>>(
                mid, W2 + (size_t)l * FF * D, b2 + (size_t)l * D, hb, FF, D, 1.0f);
            add_ln_kernel<<<SEQ, 256, 0, stream>>>(xo, hb, xo,
                g2 + (size_t)l * D, be2 + (size_t)l * D);
        }
    }
}

// Round 3
// 4582.874 us; speedup vs baseline: 3.5832x; 3.5832x over previous
//
#include <hip/hip_runtime.h>
#include <hip/hip_bf16.h>
#include <type_traits>

#define LAYERS 4
#define D      768
#define FF     3072
#define NH     12
#define HD     64
#define SEQ    4096
#define BATCH  4
#define WIN    128
#define NC     (SEQ / WIN)        // 32
#define NTOK   (BATCH * SEQ)      // 16384

using bf16 = __hip_bfloat16;
typedef short short8 __attribute__((ext_vector_type(8)));
typedef float floatx4 __attribute__((ext_vector_type(4)));

__device__ __forceinline__ float b2f(unsigned short u) {
    return __uint_as_float(((unsigned)u) << 16);
}
__device__ __forceinline__ short f2bs(float f) {
    union { bf16 h; short s; } u; u.h = __float2bfloat16(f); return u.s;
}
__device__ __forceinline__ void st_cvt(float* p, float v) { *p = v; }
__device__ __forceinline__ void st_cvt(bf16* p, float v) { *p = __float2bfloat16(v); }

// ---------------- weight transpose+convert: W[K][N] f32 -> WT[N][K] bf16 ----------
__global__ __launch_bounds__(256)
void transpose_cvt(const float* __restrict__ src, bf16* __restrict__ dst, int K, int N)
{
    __shared__ float t[32][33];
    const int n0 = blockIdx.x * 32, k0 = blockIdx.y * 32;
    const int tx = threadIdx.x & 31, ty = threadIdx.x >> 5;   // ty 0..7
    #pragma unroll
    for (int r = 0; r < 4; ++r)
        t[ty + 8 * r][tx] = src[(size_t)(k0 + ty + 8 * r) * N + n0 + tx];
    __syncthreads();
    #pragma unroll
    for (int r = 0; r < 4; ++r)
        dst[(size_t)(n0 + ty + 8 * r) * K + k0 + tx] = __float2bfloat16(t[tx][ty + 8 * r]);
}

// ---------------- MFMA GEMM: C = epi(A @ W + bias) -------------------------------
// 128x128 tile, 256 threads (4 waves), each wave 64x64 = 4x4 of 16x16x32 bf16 MFMA.
// A: [M,K] (f32 or bf16). B: PRET ? WT bf16 [N,K] : Wf f32 [K,N] (converted on the fly).
// QKV=1: scatter output to [BATCH][NH][SEQ][HD] bf16 with scale folded in.
template<int RELU, int QKV, int PRET, typename TA, typename TC>
__global__ __launch_bounds__(256)
void mfma_gemm(const TA* __restrict__ A, const float* __restrict__ Wf,
               const bf16* __restrict__ Wt, const float* __restrict__ bias,
               TC* __restrict__ C, int M, int N, int K, float scale)
{
    __shared__ __align__(16) short As[128][40];   // 32 k + 8 pad, row = 80 B
    __shared__ __align__(16) short Bs[128][40];   // stored [n][k]
    const int row0 = blockIdx.x * 128;
    const int col0 = blockIdx.y * 128;
    const int tid  = threadIdx.x;
    const int lane = tid & 63;
    const int wave = tid >> 6;
    const int quad = lane >> 4, l16 = lane & 15;
    const int mw = (wave >> 1) * 64, nw = (wave & 1) * 64;

    const int ar = tid >> 1;            // 0..127: A row / WT row
    const int ah = (tid & 1) * 16;      // 0 / 16 within the 32-wide k slab
    const int bn = tid & 127;           // non-PRET: B column
    const int bk = (tid >> 7) * 8;      // non-PRET: k sub-chunk 0 / 8

    floatx4 acc[4][4];
    const floatx4 zero = {0.f, 0.f, 0.f, 0.f};
    #pragma unroll
    for (int i = 0; i < 4; ++i)
        #pragma unroll
        for (int j = 0; j < 4; ++j) acc[i][j] = zero;

    for (int k0 = 0; k0 < K; k0 += 32) {
        __syncthreads();
        // ---- stage A tile (128 x 32) ----
        if constexpr (std::is_same<TA, float>::value) {
            const float* ap = A + (size_t)(row0 + ar) * K + k0 + ah;
            float4 a0 = *(const float4*)(ap);
            float4 a1 = *(const float4*)(ap + 4);
            float4 a2 = *(const float4*)(ap + 8);
            float4 a3 = *(const float4*)(ap + 12);
            short8 p0 = { f2bs(a0.x), f2bs(a0.y), f2bs(a0.z), f2bs(a0.w),
                          f2bs(a1.x), f2bs(a1.y), f2bs(a1.z), f2bs(a1.w) };
            short8 p1 = { f2bs(a2.x), f2bs(a2.y), f2bs(a2.z), f2bs(a2.w),
                          f2bs(a3.x), f2bs(a3.y), f2bs(a3.z), f2bs(a3.w) };
            *(short8*)&As[ar][ah]     = p0;
            *(short8*)&As[ar][ah + 8] = p1;
        } else {
            const short* ap = (const short*)A + (size_t)(row0 + ar) * K + k0 + ah;
            *(short8*)&As[ar][ah]     = *(const short8*)(ap);
            *(short8*)&As[ar][ah + 8] = *(const short8*)(ap + 8);
        }
        // ---- stage B tile (as [n][k]) ----
        if constexpr (PRET) {
            const short* bp = (const short*)Wt + (size_t)(col0 + ar) * K + k0 + ah;
            *(short8*)&Bs[ar][ah]     = *(const short8*)(bp);
            *(short8*)&Bs[ar][ah + 8] = *(const short8*)(bp + 8);
        } else {
            #pragma unroll
            for (int kc = 0; kc < 2; ++kc) {
                const int kk = bk + kc * 16;
                short tmp[8];
                #pragma unroll
                for (int e = 0; e < 8; ++e)
                    tmp[e] = f2bs(Wf[(size_t)(k0 + kk + e) * N + col0 + bn]);
                *(short8*)&Bs[bn][kk] = *(short8*)tmp;
            }
        }
        __syncthreads();
        // ---- fragments + MFMA ----
        short8 af[4], bfr[4];
        #pragma unroll
        for (int i = 0; i < 4; ++i)
            af[i] = *(const short8*)&As[mw + 16 * i + l16][quad * 8];
        #pragma unroll
        for (int j = 0; j < 4; ++j)
            bfr[j] = *(const short8*)&Bs[nw + 16 * j + l16][quad * 8];
        #pragma unroll
        for (int i = 0; i < 4; ++i)
            #pragma unroll
            for (int j = 0; j < 4; ++j)
                acc[i][j] = __builtin_amdgcn_mfma_f32_16x16x32_bf16(af[i], bfr[j], acc[i][j], 0, 0, 0);
    }
    // ---- epilogue: C/D layout col = lane&15, row = quad*4 + reg ----
    #pragma unroll
    for (int j = 0; j < 4; ++j) {
        const int c = col0 + nw + 16 * j + l16;
        const float bv = bias[c];
        #pragma unroll
        for (int i = 0; i < 4; ++i) {
            #pragma unroll
            for (int r = 0; r < 4; ++r) {
                float v = acc[i][j][r] + bv;
                if (RELU) v = fmaxf(v, 0.f);
                v *= scale;
                const int rr = row0 + mw + 16 * i + quad * 4 + r;
                if constexpr (QKV) {
                    const int b_ = rr >> 12, s_ = rr & (SEQ - 1);
                    const int h_ = c >> 6, d_ = c & (HD - 1);
                    st_cvt(&C[(((size_t)(b_ * NH + h_)) * SEQ + s_) * HD + d_], v);
                } else {
                    st_cvt(&C[(size_t)rr * N + c], v);
                }
            }
        }
    }
}

// ---------------- sliding-window attention (flash-style) -------------------------
// grid (NC, NH, BATCH), block 128 = one query row per thread.
// q,k,v: bf16 [BATCH][NH][SEQ][HD]; out: bf16 [BATCH][SEQ][D] (heads merged)
__global__ __launch_bounds__(128)
void attn_kernel(const bf16* __restrict__ q, const bf16* __restrict__ k,
                 const bf16* __restrict__ v, bf16* __restrict__ out)
{
    const int c = blockIdx.x, h = blockIdx.y, b = blockIdx.z;
    const int qi = threadIdx.x;
    const int qpos = c * WIN + qi;
    const size_t headoff = ((size_t)(b * NH + h)) * SEQ * HD;

    float qreg[HD];
    {
        const unsigned short* qrow = (const unsigned short*)q + headoff + (size_t)qpos * HD;
        #pragma unroll
        for (int e = 0; e < 8; ++e) {
            uint4 raw = *(const uint4*)(qrow + e * 8);
            const unsigned short* u = (const unsigned short*)&raw;
            #pragma unroll
            for (int t = 0; t < 8; ++t) qreg[e * 8 + t] = b2f(u[t]);
        }
    }

    float acc[HD] = {};
    float m = -1e30f, l = 0.f;

    __shared__ float Ks[32][HD];
    __shared__ float Vs[32][HD];
    const unsigned short* kb = (const unsigned short*)k + headoff;
    const unsigned short* vb = (const unsigned short*)v + headoff;

    for (int t0 = 0; t0 < 3 * WIN; t0 += 32) {
        __syncthreads();
        #pragma unroll
        for (int e = 0; e < 2; ++e) {
            const int idx = threadIdx.x + e * 128;
            const int j = idx >> 3;
            const int dd = (idx & 7) * 8;
            const int kpos = c * WIN + t0 + j - WIN;
            float kf[8] = {}, vf[8] = {};
            if (kpos >= 0 && kpos < SEQ) {
                uint4 kr = *(const uint4*)(kb + (size_t)kpos * HD + dd);
                uint4 vr = *(const uint4*)(vb + (size_t)kpos * HD + dd);
                const unsigned short* ku = (const unsigned short*)&kr;
                const unsigned short* vu = (const unsigned short*)&vr;
                #pragma unroll
                for (int t = 0; t < 8; ++t) { kf[t] = b2f(ku[t]); vf[t] = b2f(vu[t]); }
            }
            #pragma unroll
            for (int t = 0; t < 8; ++t) { Ks[j][dd + t] = kf[t]; Vs[j][dd + t] = vf[t]; }
        }
        __syncthreads();
        for (int j = 0; j < 32; ++j) {
            const int kj = t0 + j;
            const int kpos = c * WIN + kj - WIN;
            if (kj < qi || kj > qi + 2 * WIN || kpos < 0 || kpos >= SEQ) continue;
            // 4-way split dot product: breaks the 64-deep serial FMA chain
            float s0 = 0.f, s1 = 0.f, s2 = 0.f, s3 = 0.f;
            #pragma unroll
            for (int d = 0; d < HD; d += 4) {
                s0 += qreg[d + 0] * Ks[j][d + 0];
                s1 += qreg[d + 1] * Ks[j][d + 1];
                s2 += qreg[d + 2] * Ks[j][d + 2];
                s3 += qreg[d + 3] * Ks[j][d + 3];
            }
            const float s = (s0 + s1) + (s2 + s3);
            const float mn = fmaxf(m, s);
            const float corr = __expf(m - mn);
            const float p = __expf(s - mn);
            l = l * corr + p;
            #pragma unroll
            for (int d = 0; d < HD; ++d) acc[d] = acc[d] * corr + p * Vs[j][d];
            m = mn;
        }
    }
    const float inv = 1.f / l;
    bf16* orow = out + ((size_t)(b * SEQ + qpos)) * D + h * HD;
    #pragma unroll
    for (int d = 0; d < HD; ++d) orow[d] = __float2bfloat16(acc[d] * inv);
}

// ---------------- fused residual add + LayerNorm ---------------------------------
__global__ __launch_bounds__(256)
void add_ln_kernel(const float* __restrict__ xin, const bf16* __restrict__ h,
                   float* __restrict__ xout,
                   const float* __restrict__ g, const float* __restrict__ beta)
{
    const int row = blockIdx.x;
    __shared__ float buf[D];
    __shared__ float wsum[4], wsum2[4];
    const float* xr = xin + (size_t)row * D;
    const bf16* hr = h + (size_t)row * D;
    float s = 0.f, s2 = 0.f;
    #pragma unroll
    for (int e = 0; e < 3; ++e) {
        const int i = threadIdx.x + e * 256;
        const float t = xr[i] + __bfloat162float(hr[i]);
        buf[i] = t;
        s += t; s2 += t * t;
    }
    #pragma unroll
    for (int off = 32; off > 0; off >>= 1) {
        s  += __shfl_down(s, off);
        s2 += __shfl_down(s2, off);
    }
    const int wid = threadIdx.x >> 6, lane = threadIdx.x & 63;
    if (lane == 0) { wsum[wid] = s; wsum2[wid] = s2; }
    __syncthreads();
    if (threadIdx.x == 0) {
        const float S  = wsum[0] + wsum[1] + wsum[2] + wsum[3];
        const float S2 = wsum2[0] + wsum2[1] + wsum2[2] + wsum2[3];
        const float mean = S * (1.f / D);
        const float var  = S2 * (1.f / D) - mean * mean;
        wsum[0]  = mean;
        wsum2[0] = rsqrtf(var + 1e-5f);
    }
    __syncthreads();
    const float mean = wsum[0], inv = wsum2[0];
    #pragma unroll
    for (int e = 0; e < 3; ++e) {
        const int i = threadIdx.x + e * 256;
        xout[(size_t)row * D + i] = (buf[i] - mean) * inv * g[i] + beta[i];
    }
}

// ---------------- host ------------------------------------------------------------
template<int PRET>
static void run_net(const float* x0,
                    const float* Wq, const float* bq, const float* Wk, const float* bk,
                    const float* Wv, const float* bv, const float* W1, const float* b1,
                    const float* W2, const float* b2, const float* g1, const float* be1,
                    const float* g2, const float* be2, float* out,
                    bf16* qb, bf16* kb, bf16* vb, bf16* hb, bf16* mid, bf16* h2,
                    const bf16* wt, hipStream_t stream)
{
    const dim3 gD(NTOK / 128, D / 128);     // (128, 6)
    const dim3 gF(NTOK / 128, FF / 128);    // (128, 24)
    const dim3 ga(NC, NH, BATCH);
    const size_t LW = (size_t)3 * D * D + 2 * (size_t)D * FF;
    for (int l = 0; l < LAYERS; ++l) {
        const float* xin = (l == 0) ? x0 : out;
        const bf16* wtl = wt + (size_t)l * LW;
        mfma_gemm<0, 1, PRET, float, bf16><<<gD, 256, 0, stream>>>(
            xin, Wq + (size_t)l * D * D, wtl, bq + (size_t)l * D, qb, NTOK, D, D, 0.125f);
        mfma_gemm<0, 1, PRET, float, bf16><<<gD, 256, 0, stream>>>(
            xin, Wk + (size_t)l * D * D, wtl + (size_t)D * D, bk + (size_t)l * D, kb, NTOK, D, D, 1.0f);
        mfma_gemm<0, 1, PRET, float, bf16><<<gD, 256, 0, stream>>>(
            xin, Wv + (size_t)l * D * D, wtl + (size_t)2 * D * D, bv + (size_t)l * D, vb, NTOK, D, D, 1.0f);
        attn_kernel<<<ga, 128, 0, stream>>>(qb, kb, vb, hb);
        add_ln_kernel<<<NTOK, 256, 0, stream>>>(xin, hb, out,
            g1 + (size_t)l * D, be1 + (size_t)l * D);
        mfma_gemm<1, 0, PRET, float, bf16><<<gF, 256, 0, stream>>>(
            out, W1 + (size_t)l * D * FF, wtl + (size_t)3 * D * D, b1 + (size_t)l * FF,
            mid, NTOK, FF, D, 1.0f);
        mfma_gemm<0, 0, PRET, bf16, bf16><<<gD, 256, 0, stream>>>(
            mid, W2 + (size_t)l * FF * D, wtl + (size_t)3 * D * D + (size_t)D * FF,
            b2 + (size_t)l * D, h2, NTOK, D, FF, 1.0f);
        add_ln_kernel<<<NTOK, 256, 0, stream>>>(out, h2, out,
            g2 + (size_t)l * D, be2 + (size_t)l * D);
    }
}

extern "C" void kernel_launch(void* const* d_in, const int* in_sizes, int n_in,
                              void* d_out, int out_size, void* d_ws, size_t ws_size,
                              hipStream_t stream)
{
    const float* x0  = (const float*)d_in[0];
    const float* Wq  = (const float*)d_in[1];
    const float* bq  = (const float*)d_in[2];
    const float* Wk  = (const float*)d_in[3];
    const float* bk  = (const float*)d_in[4];
    const float* Wv  = (const float*)d_in[5];
    const float* bv  = (const float*)d_in[6];
    const float* W1  = (const float*)d_in[7];
    const float* b1  = (const float*)d_in[8];
    const float* W2  = (const float*)d_in[9];
    const float* b2  = (const float*)d_in[10];
    const float* g1  = (const float*)d_in[11];
    const float* be1 = (const float*)d_in[12];
    const float* g2  = (const float*)d_in[13];
    const float* be2 = (const float*)d_in[14];
    float* out = (float*)d_out;

    // workspace layout (elems of bf16):
    //   [0,QE)   qb   [QE,2QE) kb   [2QE,3QE) vb   [3QE,4QE) hb
    //   mid aliases [0,4QE)  (qkv+hb dead when FFN runs)
    //   [4QE,5QE) h2
    //   [5QE, ..) WT (optional, gated on ws_size)
    const size_t QE = (size_t)BATCH * NH * SEQ * HD;    // 12,582,912 elems
    bf16* qb  = (bf16*)d_ws;
    bf16* kb  = qb + QE;
    bf16* vb  = kb + QE;
    bf16* hb  = vb + QE;
    bf16* mid = qb;
    bf16* h2  = qb + 4 * QE;
    bf16* wt  = qb + 5 * QE;
    const size_t LW = (size_t)3 * D * D + 2 * (size_t)D * FF;   // 6,488,064 elems
    const bool pret = ws_size >= (5 * QE + (size_t)LAYERS * LW) * sizeof(bf16);

    if (pret) {
        for (int l = 0; l < LAYERS; ++l) {
            bf16* wtl = wt + (size_t)l * LW;
            transpose_cvt<<<dim3(D / 32, D / 32), 256, 0, stream>>>(
                Wq + (size_t)l * D * D, wtl, D, D);
            transpose_cvt<<<dim3(D / 32, D / 32), 256, 0, stream>>>(
                Wk + (size_t)l * D * D, wtl + (size_t)D * D, D, D);
            transpose_cvt<<<dim3(D / 32, D / 32), 256, 0, stream>>>(
                Wv + (size_t)l * D * D, wtl + (size_t)2 * D * D, D, D);
            transpose_cvt<<<dim3(FF / 32, D / 32), 256, 0, stream>>>(
                W1 + (size_t)l * D * FF, wtl + (size_t)3 * D * D, D, FF);
            transpose_cvt<<<dim3(D / 32, FF / 32), 256, 0, stream>>>(
                W2 + (size_t)l * FF * D, wtl + (size_t)3 * D * D + (size_t)D * FF, FF, D);
        }
        run_net<1>(x0, Wq, bq, Wk, bk, Wv, bv, W1, b1, W2, b2, g1, be1, g2, be2,
                   out, qb, kb, vb, hb, mid, h2, wt, stream);
    } else {
        run_net<0>(x0, Wq, bq, Wk, bk, Wv, bv, W1, b1, W2, b2, g1, be1, g2, be2,
                   out, qb, kb, vb, hb, mid, h2, wt, stream);
    }
}

// Round 4
// 2327.337 us; speedup vs baseline: 7.0558x; 1.9691x over previous
//
#include <hip/hip_runtime.h>
#include <hip/hip_bf16.h>
#include <type_traits>

#define LAYERS 4
#define D      768
#define FF     3072
#define NH     12
#define HD     64
#define SEQ    4096
#define BATCH  4
#define WIN    128
#define NC     (SEQ / WIN)        // 32
#define NTOK   (BATCH * SEQ)      // 16384

using bf16 = __hip_bfloat16;
typedef short short8 __attribute__((ext_vector_type(8)));
typedef short short4v __attribute__((ext_vector_type(4)));
typedef float floatx4 __attribute__((ext_vector_type(4)));

__device__ __forceinline__ float b2f(unsigned short u) {
    return __uint_as_float(((unsigned)u) << 16);
}
__device__ __forceinline__ short f2bs(float f) {
    union { bf16 h; short s; } u; u.h = __float2bfloat16(f); return u.s;
}
__device__ __forceinline__ void st_cvt(float* p, float v) { *p = v; }
__device__ __forceinline__ void st_cvt(bf16* p, float v) { *p = __float2bfloat16(v); }

// ---------------- weight transpose+convert: W[K][N] f32 -> WT[N][K] bf16 ----------
__global__ __launch_bounds__(256)
void transpose_cvt(const float* __restrict__ src, bf16* __restrict__ dst, int K, int N)
{
    __shared__ float t[32][33];
    const int n0 = blockIdx.x * 32, k0 = blockIdx.y * 32;
    const int tx = threadIdx.x & 31, ty = threadIdx.x >> 5;   // ty 0..7
    #pragma unroll
    for (int r = 0; r < 4; ++r)
        t[ty + 8 * r][tx] = src[(size_t)(k0 + ty + 8 * r) * N + n0 + tx];
    __syncthreads();
    #pragma unroll
    for (int r = 0; r < 4; ++r)
        dst[(size_t)(n0 + ty + 8 * r) * K + k0 + tx] = __float2bfloat16(t[tx][ty + 8 * r]);
}

// ---------------- MFMA GEMM: C = epi(A @ W + bias) -------------------------------
// 128x128 tile, 256 threads (4 waves), each wave 64x64 = 4x4 of 16x16x32 bf16 MFMA.
// A: [M,K] (f32 or bf16). B: PRET ? WT bf16 [N,K] : Wf f32 [K,N] (converted on the fly).
// OMODE 0: plain [M][N].  1: QKV scatter [BATCH][NH][SEQ][HD] (scale folded).
// OMODE 2: V^T scatter [BATCH][NH][HD][SEQ] (4 consecutive tokens packed per store).
template<int RELU, int OMODE, int PRET, typename TA, typename TC>
__global__ __launch_bounds__(256)
void mfma_gemm(const TA* __restrict__ A, const float* __restrict__ Wf,
               const bf16* __restrict__ Wt, const float* __restrict__ bias,
               TC* __restrict__ C, int M, int N, int K, float scale)
{
    __shared__ __align__(16) short As[128][40];   // 32 k + 8 pad, row = 80 B
    __shared__ __align__(16) short Bs[128][40];   // stored [n][k]
    const int row0 = blockIdx.x * 128;
    const int col0 = blockIdx.y * 128;
    const int tid  = threadIdx.x;
    const int lane = tid & 63;
    const int wave = tid >> 6;
    const int quad = lane >> 4, l16 = lane & 15;
    const int mw = (wave >> 1) * 64, nw = (wave & 1) * 64;

    const int ar = tid >> 1;            // 0..127: A row / WT row
    const int ah = (tid & 1) * 16;      // 0 / 16 within the 32-wide k slab
    const int bn = tid & 127;           // non-PRET: B column
    const int bk = (tid >> 7) * 8;      // non-PRET: k sub-chunk 0 / 8

    floatx4 acc[4][4];
    const floatx4 zero = {0.f, 0.f, 0.f, 0.f};
    #pragma unroll
    for (int i = 0; i < 4; ++i)
        #pragma unroll
        for (int j = 0; j < 4; ++j) acc[i][j] = zero;

    for (int k0 = 0; k0 < K; k0 += 32) {
        __syncthreads();
        // ---- stage A tile (128 x 32) ----
        if constexpr (std::is_same<TA, float>::value) {
            const float* ap = A + (size_t)(row0 + ar) * K + k0 + ah;
            float4 a0 = *(const float4*)(ap);
            float4 a1 = *(const float4*)(ap + 4);
            float4 a2 = *(const float4*)(ap + 8);
            float4 a3 = *(const float4*)(ap + 12);
            short8 p0 = { f2bs(a0.x), f2bs(a0.y), f2bs(a0.z), f2bs(a0.w),
                          f2bs(a1.x), f2bs(a1.y), f2bs(a1.z), f2bs(a1.w) };
            short8 p1 = { f2bs(a2.x), f2bs(a2.y), f2bs(a2.z), f2bs(a2.w),
                          f2bs(a3.x), f2bs(a3.y), f2bs(a3.z), f2bs(a3.w) };
            *(short8*)&As[ar][ah]     = p0;
            *(short8*)&As[ar][ah + 8] = p1;
        } else {
            const short* ap = (const short*)A + (size_t)(row0 + ar) * K + k0 + ah;
            *(short8*)&As[ar][ah]     = *(const short8*)(ap);
            *(short8*)&As[ar][ah + 8] = *(const short8*)(ap + 8);
        }
        // ---- stage B tile (as [n][k]) ----
        if constexpr (PRET) {
            const short* bp = (const short*)Wt + (size_t)(col0 + ar) * K + k0 + ah;
            *(short8*)&Bs[ar][ah]     = *(const short8*)(bp);
            *(short8*)&Bs[ar][ah + 8] = *(const short8*)(bp + 8);
        } else {
            #pragma unroll
            for (int kc = 0; kc < 2; ++kc) {
                const int kk = bk + kc * 16;
                short tmp[8];
                #pragma unroll
                for (int e = 0; e < 8; ++e)
                    tmp[e] = f2bs(Wf[(size_t)(k0 + kk + e) * N + col0 + bn]);
                *(short8*)&Bs[bn][kk] = *(short8*)tmp;
            }
        }
        __syncthreads();
        // ---- fragments + MFMA ----
        short8 af[4], bfr[4];
        #pragma unroll
        for (int i = 0; i < 4; ++i)
            af[i] = *(const short8*)&As[mw + 16 * i + l16][quad * 8];
        #pragma unroll
        for (int j = 0; j < 4; ++j)
            bfr[j] = *(const short8*)&Bs[nw + 16 * j + l16][quad * 8];
        #pragma unroll
        for (int i = 0; i < 4; ++i)
            #pragma unroll
            for (int j = 0; j < 4; ++j)
                acc[i][j] = __builtin_amdgcn_mfma_f32_16x16x32_bf16(af[i], bfr[j], acc[i][j], 0, 0, 0);
    }
    // ---- epilogue: C/D layout col = lane&15, row = quad*4 + reg ----
    #pragma unroll
    for (int j = 0; j < 4; ++j) {
        const int c = col0 + nw + 16 * j + l16;
        const float bv = bias[c];
        #pragma unroll
        for (int i = 0; i < 4; ++i) {
            const int rr0 = row0 + mw + 16 * i + quad * 4;
            if constexpr (OMODE == 2) {
                short4v pack;
                #pragma unroll
                for (int r = 0; r < 4; ++r)
                    pack[r] = f2bs((acc[i][j][r] + bv) * scale);
                const int b_ = rr0 >> 12, s_ = rr0 & (SEQ - 1);
                const int h_ = c >> 6, d_ = c & (HD - 1);
                *(short4v*)&C[(((size_t)(b_ * NH + h_)) * HD + d_) * SEQ + s_] = pack;
            } else {
                #pragma unroll
                for (int r = 0; r < 4; ++r) {
                    float v = acc[i][j][r] + bv;
                    if (RELU) v = fmaxf(v, 0.f);
                    v *= scale;
                    const int rr = rr0 + r;
                    if constexpr (OMODE == 1) {
                        const int b_ = rr >> 12, s_ = rr & (SEQ - 1);
                        const int h_ = c >> 6, d_ = c & (HD - 1);
                        st_cvt(&C[(((size_t)(b_ * NH + h_)) * SEQ + s_) * HD + d_], v);
                    } else {
                        st_cvt(&C[(size_t)rr * N + c], v);
                    }
                }
            }
        }
    }
}

// ---------------- MFMA sliding-window flash attention ----------------------------
// grid (NC, NH, BATCH), 256 threads = 4 waves; wave w owns queries [w*32, w*32+32).
// q,k: bf16 [B][NH][SEQ][HD]; v: bf16 [B][NH][HD][SEQ] (transposed!);
// out: bf16 [B][SEQ][D] (heads merged).
__global__ __launch_bounds__(256, 2)
void attn_mfma_kernel(const bf16* __restrict__ q, const bf16* __restrict__ k,
                      const bf16* __restrict__ v, bf16* __restrict__ out)
{
    __shared__ __align__(16) short Qs[128][72];     // [q][d]
    __shared__ __align__(16) short Ks[64][72];      // [key][d]
    __shared__ __align__(16) short Vs[64][72];      // [d][key]  (V^T)
    __shared__ __align__(16) short Ps[4][32][72];   // per-wave P [q][key]

    const int c = blockIdx.x, h = blockIdx.y, b = blockIdx.z;
    const int tid = threadIdx.x;
    const int wave = tid >> 6, lane = tid & 63;
    const int quad = lane >> 4, l16 = lane & 15;
    const int qbase = wave * 32;

    const unsigned short* qg = (const unsigned short*)q + ((size_t)(b * NH + h)) * SEQ * HD;
    const unsigned short* kg = (const unsigned short*)k + ((size_t)(b * NH + h)) * SEQ * HD;
    const unsigned short* vg = (const unsigned short*)v + ((size_t)(b * NH + h)) * HD * SEQ;

    // ---- stage Q (128 x 64) ----
    #pragma unroll
    for (int e = 0; e < 4; ++e) {
        const int idx = tid + e * 256;
        const int row = idx >> 3, d0 = (idx & 7) * 8;
        *(uint4*)&Qs[row][d0] = *(const uint4*)(qg + (size_t)(c * WIN + row) * HD + d0);
    }

    floatx4 O[2][4];
    const floatx4 zero = {0.f, 0.f, 0.f, 0.f};
    float m_i[2][4], l_i[2][4];
    #pragma unroll
    for (int i = 0; i < 2; ++i)
        #pragma unroll
        for (int r = 0; r < 4; ++r) { m_i[i][r] = -1e30f; l_i[i][r] = 0.f; }
    #pragma unroll
    for (int i = 0; i < 2; ++i)
        #pragma unroll
        for (int dj = 0; dj < 4; ++dj) O[i][dj] = zero;

    for (int sl = 0; sl < 6; ++sl) {
        const int s0 = sl * 64;                      // chunk-local key offset
        const int kpos0 = c * WIN - WIN + s0;        // global key pos of slab start
        if (kpos0 < 0 || kpos0 >= SEQ) continue;     // slab fully OOB (block-uniform)
        __syncthreads();
        // ---- stage K slab (64 keys x 64 d) and V^T slab (64 d x 64 keys) ----
        #pragma unroll
        for (int e = 0; e < 2; ++e) {
            const int idx = tid + e * 256;
            const int row = idx >> 3, d0 = (idx & 7) * 8;
            *(uint4*)&Ks[row][d0] = *(const uint4*)(kg + (size_t)(kpos0 + row) * HD + d0);
            *(uint4*)&Vs[row][d0] = *(const uint4*)(vg + (size_t)row * SEQ + kpos0 + d0);
        }
        __syncthreads();
        // ---- scores S = Q K^T : 32q x 64k per wave ----
        short8 aq[2][2], bk2[4][2];
        #pragma unroll
        for (int i = 0; i < 2; ++i)
            #pragma unroll
            for (int hh = 0; hh < 2; ++hh)
                aq[i][hh] = *(const short8*)&Qs[qbase + 16 * i + l16][hh * 32 + quad * 8];
        #pragma unroll
        for (int j = 0; j < 4; ++j)
            #pragma unroll
            for (int hh = 0; hh < 2; ++hh)
                bk2[j][hh] = *(const short8*)&Ks[16 * j + l16][hh * 32 + quad * 8];
        floatx4 sc[2][4];
        #pragma unroll
        for (int i = 0; i < 2; ++i)
            #pragma unroll
            for (int j = 0; j < 4; ++j) {
                floatx4 t = __builtin_amdgcn_mfma_f32_16x16x32_bf16(aq[i][0], bk2[j][0], zero, 0, 0, 0);
                sc[i][j]  = __builtin_amdgcn_mfma_f32_16x16x32_bf16(aq[i][1], bk2[j][1], t, 0, 0, 0);
            }
        // ---- online softmax (C-layout: row=quad*4+r, col=l16) ----
        #pragma unroll
        for (int i = 0; i < 2; ++i) {
            #pragma unroll
            for (int r = 0; r < 4; ++r) {
                const int qq = qbase + 16 * i + quad * 4 + r;
                float sv[4];
                float mx = -1e30f;
                #pragma unroll
                for (int j = 0; j < 4; ++j) {
                    const int kj = s0 + 16 * j + l16;
                    const bool ok = (kj >= qq) && (kj <= qq + 2 * WIN);
                    const float s = ok ? sc[i][j][r] : -1e30f;
                    sv[j] = s;
                    mx = fmaxf(mx, s);
                }
                mx = fmaxf(mx, __shfl_xor(mx, 1));
                mx = fmaxf(mx, __shfl_xor(mx, 2));
                mx = fmaxf(mx, __shfl_xor(mx, 4));
                mx = fmaxf(mx, __shfl_xor(mx, 8));
                const float mn = fmaxf(m_i[i][r], mx);
                const float corr = __expf(m_i[i][r] - mn);
                m_i[i][r] = mn;
                float ps = 0.f;
                #pragma unroll
                for (int j = 0; j < 4; ++j) {
                    const float p = (sv[j] > -0.9e30f) ? __expf(sv[j] - mn) : 0.f;
                    ps += p;
                    Ps[wave][16 * i + quad * 4 + r][16 * j + l16] = f2bs(p);
                }
                ps += __shfl_xor(ps, 1);
                ps += __shfl_xor(ps, 2);
                ps += __shfl_xor(ps, 4);
                ps += __shfl_xor(ps, 8);
                l_i[i][r] = l_i[i][r] * corr + ps;
                #pragma unroll
                for (int dj = 0; dj < 4; ++dj) O[i][dj][r] *= corr;
            }
        }
        // ---- O += P V  (wave-private P, no barrier needed) ----
        short8 ap[2][2], bv2[4][2];
        #pragma unroll
        for (int i = 0; i < 2; ++i)
            #pragma unroll
            for (int hh = 0; hh < 2; ++hh)
                ap[i][hh] = *(const short8*)&Ps[wave][16 * i + l16][hh * 32 + quad * 8];
        #pragma unroll
        for (int dj = 0; dj < 4; ++dj)
            #pragma unroll
            for (int hh = 0; hh < 2; ++hh)
                bv2[dj][hh] = *(const short8*)&Vs[16 * dj + l16][hh * 32 + quad * 8];
        #pragma unroll
        for (int i = 0; i < 2; ++i)
            #pragma unroll
            for (int dj = 0; dj < 4; ++dj) {
                O[i][dj] = __builtin_amdgcn_mfma_f32_16x16x32_bf16(ap[i][0], bv2[dj][0], O[i][dj], 0, 0, 0);
                O[i][dj] = __builtin_amdgcn_mfma_f32_16x16x32_bf16(ap[i][1], bv2[dj][1], O[i][dj], 0, 0, 0);
            }
    }
    // ---- epilogue ----
    bf16* og = out + ((size_t)b * SEQ + c * WIN) * D + h * HD;
    #pragma unroll
    for (int i = 0; i < 2; ++i) {
        #pragma unroll
        for (int r = 0; r < 4; ++r) {
            const float inv = 1.f / l_i[i][r];
            const int qq = qbase + 16 * i + quad * 4 + r;
            #pragma unroll
            for (int dj = 0; dj < 4; ++dj)
                og[(size_t)qq * D + 16 * dj + l16] = __float2bfloat16(O[i][dj][r] * inv);
        }
    }
}

// ---------------- fused residual add + LayerNorm ---------------------------------
__global__ __launch_bounds__(256)
void add_ln_kernel(const float* __restrict__ xin, const bf16* __restrict__ h,
                   float* __restrict__ xout,
                   const float* __restrict__ g, const float* __restrict__ beta)
{
    const int row = blockIdx.x;
    __shared__ float buf[D];
    __shared__ float wsum[4], wsum2[4];
    const float* xr = xin + (size_t)row * D;
    const bf16* hr = h + (size_t)row * D;
    float s = 0.f, s2 = 0.f;
    #pragma unroll
    for (int e = 0; e < 3; ++e) {
        const int i = threadIdx.x + e * 256;
        const float t = xr[i] + __bfloat162float(hr[i]);
        buf[i] = t;
        s += t; s2 += t * t;
    }
    #pragma unroll
    for (int off = 32; off > 0; off >>= 1) {
        s  += __shfl_down(s, off);
        s2 += __shfl_down(s2, off);
    }
    const int wid = threadIdx.x >> 6, lane = threadIdx.x & 63;
    if (lane == 0) { wsum[wid] = s; wsum2[wid] = s2; }
    __syncthreads();
    if (threadIdx.x == 0) {
        const float S  = wsum[0] + wsum[1] + wsum[2] + wsum[3];
        const float S2 = wsum2[0] + wsum2[1] + wsum2[2] + wsum2[3];
        const float mean = S * (1.f / D);
        const float var  = S2 * (1.f / D) - mean * mean;
        wsum[0]  = mean;
        wsum2[0] = rsqrtf(var + 1e-5f);
    }
    __syncthreads();
    const float mean = wsum[0], inv = wsum2[0];
    #pragma unroll
    for (int e = 0; e < 3; ++e) {
        const int i = threadIdx.x + e * 256;
        xout[(size_t)row * D + i] = (buf[i] - mean) * inv * g[i] + beta[i];
    }
}

// ---------------- host ------------------------------------------------------------
template<int PRET>
static void run_net(const float* x0,
                    const float* Wq, const float* bq, const float* Wk, const float* bk,
                    const float* Wv, const float* bv, const float* W1, const float* b1,
                    const float* W2, const float* b2, const float* g1, const float* be1,
                    const float* g2, const float* be2, float* out,
                    bf16* qb, bf16* kb, bf16* vb, bf16* hb, bf16* mid, bf16* h2,
                    const bf16* wt, hipStream_t stream)
{
    const dim3 gD(NTOK / 128, D / 128);     // (128, 6)
    const dim3 gF(NTOK / 128, FF / 128);    // (128, 24)
    const dim3 ga(NC, NH, BATCH);
    const size_t LW = (size_t)3 * D * D + 2 * (size_t)D * FF;
    for (int l = 0; l < LAYERS; ++l) {
        const float* xin = (l == 0) ? x0 : out;
        const bf16* wtl = wt + (size_t)l * LW;
        mfma_gemm<0, 1, PRET, float, bf16><<<gD, 256, 0, stream>>>(
            xin, Wq + (size_t)l * D * D, wtl, bq + (size_t)l * D, qb, NTOK, D, D, 0.125f);
        mfma_gemm<0, 1, PRET, float, bf16><<<gD, 256, 0, stream>>>(
            xin, Wk + (size_t)l * D * D, wtl + (size_t)D * D, bk + (size_t)l * D, kb, NTOK, D, D, 1.0f);
        mfma_gemm<0, 2, PRET, float, bf16><<<gD, 256, 0, stream>>>(
            xin, Wv + (size_t)l * D * D, wtl + (size_t)2 * D * D, bv + (size_t)l * D, vb, NTOK, D, D, 1.0f);
        attn_mfma_kernel<<<ga, 256, 0, stream>>>(qb, kb, vb, hb);
        add_ln_kernel<<<NTOK, 256, 0, stream>>>(xin, hb, out,
            g1 + (size_t)l * D, be1 + (size_t)l * D);
        mfma_gemm<1, 0, PRET, float, bf16><<<gF, 256, 0, stream>>>(
            out, W1 + (size_t)l * D * FF, wtl + (size_t)3 * D * D, b1 + (size_t)l * FF,
            mid, NTOK, FF, D, 1.0f);
        mfma_gemm<0, 0, PRET, bf16, bf16><<<gD, 256, 0, stream>>>(
            mid, W2 + (size_t)l * FF * D, wtl + (size_t)3 * D * D + (size_t)D * FF,
            b2 + (size_t)l * D, h2, NTOK, D, FF, 1.0f);
        add_ln_kernel<<<NTOK, 256, 0, stream>>>(out, h2, out,
            g2 + (size_t)l * D, be2 + (size_t)l * D);
    }
}

extern "C" void kernel_launch(void* const* d_in, const int* in_sizes, int n_in,
                              void* d_out, int out_size, void* d_ws, size_t ws_size,
                              hipStream_t stream)
{
    const float* x0  = (const float*)d_in[0];
    const float* Wq  = (const float*)d_in[1];
    const float* bq  = (const float*)d_in[2];
    const float* Wk  = (const float*)d_in[3];
    const float* bk  = (const float*)d_in[4];
    const float* Wv  = (const float*)d_in[5];
    const float* bv  = (const float*)d_in[6];
    const float* W1  = (const float*)d_in[7];
    const float* b1  = (const float*)d_in[8];
    const float* W2  = (const float*)d_in[9];
    const float* b2  = (const float*)d_in[10];
    const float* g1  = (const float*)d_in[11];
    const float* be1 = (const float*)d_in[12];
    const float* g2  = (const float*)d_in[13];
    const float* be2 = (const float*)d_in[14];
    float* out = (float*)d_out;

    // workspace layout (elems of bf16):
    //   [0,QE) qb  [QE,2QE) kb  [2QE,3QE) vb(V^T)  [3QE,4QE) hb
    //   mid aliases [0,4QE) (qkv+hb dead when FFN runs)
    //   [4QE,5QE) h2
    //   [5QE,..) WT (optional, gated on ws_size)
    const size_t QE = (size_t)BATCH * NH * SEQ * HD;    // 12,582,912 elems
    bf16* qb  = (bf16*)d_ws;
    bf16* kb  = qb + QE;
    bf16* vb  = kb + QE;
    bf16* hb  = vb + QE;
    bf16* mid = qb;
    bf16* h2  = qb + 4 * QE;
    bf16* wt  = qb + 5 * QE;
    const size_t LW = (size_t)3 * D * D + 2 * (size_t)D * FF;   // 6,488,064 elems
    const bool pret = ws_size >= (5 * QE + (size_t)LAYERS * LW) * sizeof(bf16);

    if (pret) {
        for (int l = 0; l < LAYERS; ++l) {
            bf16* wtl = wt + (size_t)l * LW;
            transpose_cvt<<<dim3(D / 32, D / 32), 256, 0, stream>>>(
                Wq + (size_t)l * D * D, wtl, D, D);
            transpose_cvt<<<dim3(D / 32, D / 32), 256, 0, stream>>>(
                Wk + (size_t)l * D * D, wtl + (size_t)D * D, D, D);
            transpose_cvt<<<dim3(D / 32, D / 32), 256, 0, stream>>>(
                Wv + (size_t)l * D * D, wtl + (size_t)2 * D * D, D, D);
            transpose_cvt<<<dim3(FF / 32, D / 32), 256, 0, stream>>>(
                W1 + (size_t)l * D * FF, wtl + (size_t)3 * D * D, D, FF);
            transpose_cvt<<<dim3(D / 32, FF / 32), 256, 0, stream>>>(
                W2 + (size_t)l * FF * D, wtl + (size_t)3 * D * D + (size_t)D * FF, FF, D);
        }
        run_net<1>(x0, Wq, bq, Wk, bk, Wv, bv, W1, b1, W2, b2, g1, be1, g2, be2,
                   out, qb, kb, vb, hb, mid, h2, wt, stream);
    } else {
        run_net<0>(x0, Wq, bq, Wk, bk, Wv, bv, W1, b1, W2, b2, g1, be1, g2, be2,
                   out, qb, kb, vb, hb, mid, h2, wt, stream);
    }
}